// Round 2
// baseline (366.540 us; speedup 1.0000x reference)
//
#include <hip/hip_runtime.h>
#include <hip/hip_bf16.h>
#include <math.h>

// N=500,000 nodes, E=16,000,000 edges, D_COEF=1, EPS=1e-12.
// Outputs (fp32, flat): v [N,2] then torque [N,1].
// torque = w0 * sum_sin / max(||sum||, eps)  (count cancels in normalize).
//
// R2: global fp32 atomics = ~32B memory-side RMW each -> binning.
// R3: two-phase binning -> 408 us.
// R4: LDS counting-sort writeout + packed u64 LDS atomics -> 278 us.
// R5: theta_q carried in entry -> 264 us (phase 1 eats the 16M random
//     gathers; phase 2 pure stream).
// R6 FAILED: 1024thr/launch_bounds(1024,8) -> VGPR 16 + scratch spills,
//     186 us. Falsified the occupancy theory: 2.6x waves, slower. The
//     gather is L1-miss-throughput-bound per CU, occupancy-independent.
// R7: entry = (local_dst:11 | src:19)  (N < 2^19). Phase 1 = pure
//     stream + LDS sort, touches no theta. Phase 2 absorbs the random
//     gather, overlapping it with sincos VALU + DS atomics. Native
//     v_sin/v_cos (args small). Nontemporal on the bins stream so it
//     doesn't evict L2-resident theta (2MB, fits per-XCD L2).
//
// ws layout: [0..256) uint cursors (1 KB), then uint bins[NB * CAP].

#define NBITS_S   19
#define SRC_MASK  ((1u << NBITS_S) - 1)
#define BIN_SHIFT 11
#define BIN_W     2048
#define NB        245                  // ceil(500000/2048)
#define CAP       67584                // mean 65306 + ~9 sigma, mult of 4
#define K_BATCH   8192                 // edges per phase-1 block
#define EPT       32                   // edges per thread, phase 1
#define SCALE_F   524288.0f            // 2^19 (phase-2 fixed-point)
#define INV_SCALE (1.0f / 524288.0f)
#define INV_2PI   0.15915494309189535f

typedef unsigned uint4_v __attribute__((ext_vector_type(4)));

__global__ void init_cursors(unsigned* __restrict__ cur) {
    int b = blockIdx.x * blockDim.x + threadIdx.x;
    if (b < 256) cur[b] = (b < NB) ? (unsigned)b * CAP : 0u;
}

__global__ __launch_bounds__(256) void bin_edges_sort(
        const int4* __restrict__ src4, const int4* __restrict__ dst4,
        unsigned* __restrict__ bins, unsigned* __restrict__ cursor, int E)
{
    __shared__ unsigned      sorted[K_BATCH];   // 32 KB
    __shared__ unsigned char sbin[K_BATCH];     //  8 KB
    __shared__ unsigned      hist[256];
    __shared__ unsigned      base[256];
    __shared__ unsigned      gbase[256];
    __shared__ unsigned      lcnt[256];

    const int tid   = threadIdx.x;
    const int bb    = blockIdx.x;
    const int e0    = bb * K_BATCH;
    const int nval  = min(K_BATCH, E - e0);
    const int E4    = E >> 2;
    const int base4 = e0 >> 2;

    hist[tid] = 0u;
    lcnt[tid] = 0u;
    __syncthreads();

    // ---- A: issue all src+dst quad loads up front (pure stream, MLP) ----
    int4 sQ[EPT / 4], dQ[EPT / 4];
#pragma unroll
    for (int j = 0; j < EPT / 4; ++j) {
        const int idx4 = base4 + j * 256 + tid;
        if (idx4 < E4) {
            sQ[j] = src4[idx4];
            dQ[j] = dst4[idx4];
        } else {
            sQ[j] = make_int4(0, 0, 0, 0);
            dQ[j] = make_int4(0, 0, 0, 0);
        }
    }

    // ---- B: build entries (local_dst:11 | src:19), histogram ----
    unsigned ent[EPT];
    unsigned bn[EPT];          // bin id, 0xFF = invalid
#pragma unroll
    for (int j = 0; j < EPT / 4; ++j) {
        const int idx4 = base4 + j * 256 + tid;
        const int q0   = j * 4;
        if (idx4 < E4) {
            const int dd[4] = {dQ[j].x, dQ[j].y, dQ[j].z, dQ[j].w};
            const int ss[4] = {sQ[j].x, sQ[j].y, sQ[j].z, sQ[j].w};
#pragma unroll
            for (int k = 0; k < 4; ++k) {
                const unsigned b = (unsigned)dd[k] >> BIN_SHIFT;
                ent[q0 + k] = ((unsigned)(dd[k] & (BIN_W - 1)) << NBITS_S)
                              | (unsigned)ss[k];
                bn[q0 + k]  = b;
                atomicAdd(&hist[b], 1u);
            }
        } else {
#pragma unroll
            for (int k = 0; k < 4; ++k) bn[q0 + k] = 0xFFu;
        }
    }
    __syncthreads();

    // ---- C: exclusive prefix scan of hist, single wave (lane owns 4 bins)
    if (tid < 64) {
        unsigned h[4];
#pragma unroll
        for (int k = 0; k < 4; ++k) h[k] = hist[tid * 4 + k];
        const unsigned tot = h[0] + h[1] + h[2] + h[3];
        unsigned s = tot;
#pragma unroll
        for (int off = 1; off < 64; off <<= 1) {
            const unsigned y = __shfl_up(s, off);
            if (tid >= off) s += y;
        }
        unsigned run = s - tot;              // exclusive across lanes
#pragma unroll
        for (int k = 0; k < 4; ++k) {
            base[tid * 4 + k] = run;
            run += h[k];
        }
#pragma unroll
        for (int k = 0; k < 4; ++k)
            if (h[k]) gbase[tid * 4 + k] = atomicAdd(&cursor[tid * 4 + k], h[k]);
    }
    __syncthreads();

    // ---- D: scatter into sorted LDS buffer ----
#pragma unroll
    for (int q = 0; q < EPT; ++q) {
        if (bn[q] != 0xFFu) {
            const unsigned b   = bn[q];
            const unsigned pos = base[b] + atomicAdd(&lcnt[b], 1u);
            sorted[pos] = ent[q];
            sbin[pos]   = (unsigned char)b;
        }
    }
    __syncthreads();

    // ---- E: coalesced write-out (contiguous run per bin), nontemporal ----
    for (int l = tid; l < nval; l += 256) {
        const unsigned b    = sbin[l];
        const unsigned gpos = gbase[b] + ((unsigned)l - base[b]);
        if (gpos < (b + 1u) * CAP)          // ~9-sigma overflow guard
            __builtin_nontemporal_store(sorted[l], &bins[gpos]);
    }
}

__global__ __launch_bounds__(1024) void reduce_bins(
        const float* __restrict__ theta, const unsigned* __restrict__ bins,
        const unsigned* __restrict__ cursor, const float* __restrict__ v0p,
        const float* __restrict__ w0p, float* __restrict__ out, int N)
{
    __shared__ float th[BIN_W];                         //  8 KB
    __shared__ unsigned long long acc[BIN_W];           // 16 KB
    const int b     = blockIdx.x;
    const int tid   = threadIdx.x;
    const int node0 = b * BIN_W;
    const int W     = min(BIN_W, N - node0);

    for (int j = tid; j < BIN_W; j += 1024) {
        th[j]  = (j < W) ? theta[node0 + j] : 0.f;
        acc[j] = 0ull;
    }
    __syncthreads();

    const unsigned  base  = (unsigned)b * CAP;
    const int       count = (int)(cursor[b] - base);
    const unsigned* bp    = bins + base;

    // stream 8 entries/thread/iter: 2 nontemporal uint4 loads, then 8
    // theta[src] gathers issued together (L2-resident), then sincos+pack.
    const int CH = 1024 * 8;
    int i0 = 0;
    for (; i0 + CH <= count; i0 += CH) {
        const uint4_v ea = __builtin_nontemporal_load(
            (const uint4_v*)(bp + i0 + tid * 4));
        const uint4_v eb = __builtin_nontemporal_load(
            (const uint4_v*)(bp + i0 + 4096 + tid * 4));
        const unsigned ee[8] = {ea.x, ea.y, ea.z, ea.w, eb.x, eb.y, eb.z, eb.w};
        float ts[8];
#pragma unroll
        for (int k = 0; k < 8; ++k) ts[k] = theta[ee[k] & SRC_MASK];
#pragma unroll
        for (int k = 0; k < 8; ++k) {
            const unsigned l = ee[k] >> NBITS_S;
            const float r  = (ts[k] - th[l]) * INV_2PI;
            const float sn = __builtin_amdgcn_sinf(r);
            const float cs = __builtin_amdgcn_cosf(r);
            const unsigned cq = (unsigned)((cs + 1.0f) * SCALE_F + 0.5f);
            const unsigned sq = (unsigned)((sn + 1.0f) * SCALE_F + 0.5f);
            atomicAdd(&acc[l], (1ull << 56) | ((unsigned long long)cq << 28)
                               | (unsigned long long)sq);
        }
    }
    for (int i = i0 + tid; i < count; i += 1024) {
        const unsigned e = __builtin_nontemporal_load(bp + i);
        const unsigned l = e >> NBITS_S;
        const float ts = theta[e & SRC_MASK];
        const float r  = (ts - th[l]) * INV_2PI;
        const float sn = __builtin_amdgcn_sinf(r);
        const float cs = __builtin_amdgcn_cosf(r);
        const unsigned cq = (unsigned)((cs + 1.0f) * SCALE_F + 0.5f);
        const unsigned sq = (unsigned)((sn + 1.0f) * SCALE_F + 0.5f);
        atomicAdd(&acc[l], (1ull << 56) | ((unsigned long long)cq << 28)
                           | (unsigned long long)sq);
    }
    __syncthreads();

    // epilogue: unpack, v and torque (th[] is exact fp32 theta)
    const float v0 = *v0p, w0 = *w0p;
    for (int j = tid; j < W; j += 1024) {
        const float t = th[j];
        const float rr = t * INV_2PI;
        const float sn = __builtin_amdgcn_sinf(rr);
        const float cs = __builtin_amdgcn_cosf(rr);
        ((float2*)out)[node0 + j] = make_float2(v0 * cs, v0 * sn);
        const unsigned long long P = acc[j];
        const float c  = (float)(unsigned)(P >> 56);
        const float xs = (float)(unsigned)((P >> 28) & 0xFFFFFFFull) * INV_SCALE - c;
        const float ys = (float)(unsigned)(P & 0xFFFFFFFull) * INV_SCALE - c;
        const float nrm = sqrtf(xs * xs + ys * ys);
        out[2 * N + node0 + j] = w0 * (ys / fmaxf(nrm, 1e-12f));
    }
}

// ---------- fallback path (round-2 kernels) if ws is too small ----------

__global__ void zero_ws_kernel(float4* __restrict__ ws, int n4) {
    int i = blockIdx.x * blockDim.x + threadIdx.x;
    if (i < n4) ws[i] = make_float4(0.f, 0.f, 0.f, 0.f);
}

__global__ void edge_kernel_fb(const float* __restrict__ theta,
                               const int4* __restrict__ src4,
                               const int4* __restrict__ dst4,
                               float2* __restrict__ acc, int E8) {
    int i = blockIdx.x * blockDim.x + threadIdx.x;
    if (i >= E8) return;
    const int4 s0 = src4[2 * i], s1 = src4[2 * i + 1];
    const int4 d0 = dst4[2 * i], d1 = dst4[2 * i + 1];
    const int ss[8] = {s0.x, s0.y, s0.z, s0.w, s1.x, s1.y, s1.z, s1.w};
    const int dd[8] = {d0.x, d0.y, d0.z, d0.w, d1.x, d1.y, d1.z, d1.w};
    float ts[8], td[8];
#pragma unroll
    for (int k = 0; k < 8; ++k) ts[k] = theta[ss[k]];
#pragma unroll
    for (int k = 0; k < 8; ++k) td[k] = theta[dd[k]];
#pragma unroll
    for (int k = 0; k < 8; ++k) {
        float sn, cs;
        __sincosf(ts[k] - td[k], &sn, &cs);
        atomicAdd(&acc[dd[k]].x, cs);
        atomicAdd(&acc[dd[k]].y, sn);
    }
}

__global__ void node_kernel_fb(const float* __restrict__ theta,
                               const float2* __restrict__ acc,
                               const float* __restrict__ v0p,
                               const float* __restrict__ w0p,
                               float* __restrict__ out, int N) {
    int i = blockIdx.x * blockDim.x + threadIdx.x;
    if (i >= N) return;
    const float v0 = *v0p, w0 = *w0p;
    float sn, cs;
    __sincosf(theta[i], &sn, &cs);
    ((float2*)out)[i] = make_float2(v0 * cs, v0 * sn);
    const float2 a = acc[i];
    const float nrm = sqrtf(a.x * a.x + a.y * a.y);
    out[2 * N + i] = w0 * (a.y / fmaxf(nrm, 1e-12f));
}

extern "C" void kernel_launch(void* const* d_in, const int* in_sizes, int n_in,
                              void* d_out, int out_size, void* d_ws, size_t ws_size,
                              hipStream_t stream) {
    const float* theta = (const float*)d_in[0];
    const int*   src   = (const int*)d_in[1];
    const int*   dst   = (const int*)d_in[2];
    const float* v0p   = (const float*)d_in[3];
    const float* w0p   = (const float*)d_in[4];
    float*       out   = (float*)d_out;

    const int N = in_sizes[0];   // 500,000
    const int E = in_sizes[1];   // 16,000,000

    const size_t need = 1024 + (size_t)NB * CAP * sizeof(unsigned);

    if (ws_size >= need && N <= NB * BIN_W && N <= (1 << NBITS_S)) {
        unsigned* cursor = (unsigned*)d_ws;
        unsigned* bins   = cursor + 256;

        init_cursors<<<1, 256, 0, stream>>>(cursor);

        const int nblk = (E + K_BATCH - 1) / K_BATCH;   // 1954
        bin_edges_sort<<<nblk, 256, 0, stream>>>((const int4*)src,
                                                 (const int4*)dst,
                                                 bins, cursor, E);

        const int nbins = (N + BIN_W - 1) / BIN_W;      // 245
        reduce_bins<<<nbins, 1024, 0, stream>>>(theta, bins, cursor,
                                                v0p, w0p, out, N);
    } else {
        float2* acc = (float2*)d_ws;
        {
            const int n4 = (2 * N) / 4;
            zero_ws_kernel<<<(n4 + 255) / 256, 256, 0, stream>>>((float4*)d_ws, n4);
        }
        {
            const int E8 = E / 8;
            edge_kernel_fb<<<(E8 + 255) / 256, 256, 0, stream>>>(
                theta, (const int4*)src, (const int4*)dst, acc, E8);
        }
        node_kernel_fb<<<(N + 255) / 256, 256, 0, stream>>>(theta, acc, v0p, w0p,
                                                            out, N);
    }
}

// Round 3
// 327.331 us; speedup vs baseline: 1.1198x; 1.1198x over previous
//
#include <hip/hip_runtime.h>
#include <hip/hip_bf16.h>
#include <math.h>

// N=500,000 nodes, E=16,000,000 edges, D_COEF=1, EPS=1e-12.
// Outputs (fp32, flat): v [N,2] then torque [N,1].
// torque = w0 * sum_sin / max(||sum||, eps)  (count cancels in normalize).
//
// R2: global fp32 atomics = ~32B memory-side RMW each -> binning.
// R3: two-phase binning -> 408 us.
// R4: LDS counting-sort writeout + packed u64 LDS atomics -> 278 us.
// R5: theta_q carried in entry -> 264 us (gather hidden in phase 1,
//     phase 2 pure stream).
// R6 FAILED: 1024thr -> VGPR 16 + scratch spills. Occupancy theory dead:
//     2.6x waves, slower.
// R7 FAILED: gather moved to phase 2 (+75 us there, -0 in phase 1 -- it
//     was fully hidden), nt stores amplified writes (77->93 MB, +28 us).
//     Diagnosis: phase 1 is LDS-ATOMIC-THROUGHPUT bound (32M DS atomics
//     = hist + lcnt), not gather/memory bound.
// R8: halve the DS atomics: atomicAdd(&hist[b],1) already RETURNS the
//     edge's rank within (block,bin). Pack (bin:8|rank:13), scatter with
//     pos = base[b]+rank -- lcnt eliminated. Normal stores. theta_q back
//     in entry; native v_sin/v_cos in phase 2.
//
// ws layout: [0..256) uint cursors (1 KB), then uint bins[NB * CAP].

#define NBITS_Q   21
#define Q_MASK    ((1u << NBITS_Q) - 1)
#define Q_SCALE   131072.0f            // 2^21 / 16
#define Q_INV     (1.0f / 131072.0f)
#define BIN_SHIFT 11
#define BIN_W     2048
#define NB        245                  // ceil(500000/2048)
#define CAP       67584                // mean 65306 + ~9 sigma, mult of 4
#define K_BATCH   8192                 // edges per phase-1 block
#define EPT       32                   // edges per thread, phase 1
#define SCALE_F   524288.0f            // 2^19 (phase-2 fixed-point)
#define INV_SCALE (1.0f / 524288.0f)
#define INV_2PI   0.15915494309189535f

typedef unsigned uint4_v __attribute__((ext_vector_type(4)));

__global__ void init_cursors(unsigned* __restrict__ cur) {
    int b = blockIdx.x * blockDim.x + threadIdx.x;
    if (b < 256) cur[b] = (b < NB) ? (unsigned)b * CAP : 0u;
}

__global__ __launch_bounds__(256) void bin_edges_sort(
        const float* __restrict__ theta,
        const int4* __restrict__ src4, const int4* __restrict__ dst4,
        unsigned* __restrict__ bins, unsigned* __restrict__ cursor, int E)
{
    __shared__ unsigned      sorted[K_BATCH];   // 32 KB
    __shared__ unsigned char sbin[K_BATCH];     //  8 KB
    __shared__ unsigned      hist[256];
    __shared__ unsigned      base[256];
    __shared__ unsigned      gbase[256];

    const int tid   = threadIdx.x;
    const int bb    = blockIdx.x;
    const int e0    = bb * K_BATCH;
    const int nval  = min(K_BATCH, E - e0);
    const int E4    = E >> 2;
    const int base4 = e0 >> 2;

    hist[tid] = 0u;
    __syncthreads();

    // ---- A: load all src quads, then issue all 32 theta gathers (MLP) ----
    int4 sQ[EPT / 4];
#pragma unroll
    for (int j = 0; j < EPT / 4; ++j) {
        const int idx4 = base4 + j * 256 + tid;
        sQ[j] = (idx4 < E4) ? src4[idx4] : make_int4(0, 0, 0, 0);
    }
    float tq[EPT];
#pragma unroll
    for (int j = 0; j < EPT / 4; ++j) {
        tq[j * 4 + 0] = theta[sQ[j].x];
        tq[j * 4 + 1] = theta[sQ[j].y];
        tq[j * 4 + 2] = theta[sQ[j].z];
        tq[j * 4 + 3] = theta[sQ[j].w];
    }

    // ---- B: load dst quads, build entries, histogram w/ rank capture ----
    unsigned ent[EPT];
    unsigned bnrk[EPT];        // (bin:8 | rank:13); 0xFFFFFFFF = invalid
#pragma unroll
    for (int j = 0; j < EPT / 4; ++j) {
        const int idx4 = base4 + j * 256 + tid;
        const int q0   = j * 4;
        if (idx4 < E4) {
            const int4 d = dst4[idx4];
            const int dd[4] = {d.x, d.y, d.z, d.w};
#pragma unroll
            for (int k = 0; k < 4; ++k) {
                const unsigned b    = (unsigned)dd[k] >> BIN_SHIFT;
                const unsigned rank = atomicAdd(&hist[b], 1u);
                bnrk[q0 + k] = (b << 16) | rank;
                float qf = (tq[q0 + k] + 8.0f) * Q_SCALE + 0.5f;
                qf = fminf(fmaxf(qf, 0.0f), 2097151.0f);
                ent[q0 + k] = ((unsigned)(dd[k] & (BIN_W - 1)) << NBITS_Q)
                              | (unsigned)qf;
            }
        } else {
#pragma unroll
            for (int k = 0; k < 4; ++k) bnrk[q0 + k] = 0xFFFFFFFFu;
        }
    }
    __syncthreads();

    // ---- C: exclusive prefix scan of hist, single wave (lane owns 4 bins)
    if (tid < 64) {
        unsigned h[4];
#pragma unroll
        for (int k = 0; k < 4; ++k) h[k] = hist[tid * 4 + k];
        const unsigned tot = h[0] + h[1] + h[2] + h[3];
        unsigned s = tot;
#pragma unroll
        for (int off = 1; off < 64; off <<= 1) {
            const unsigned y = __shfl_up(s, off);
            if (tid >= off) s += y;
        }
        unsigned run = s - tot;              // exclusive across lanes
#pragma unroll
        for (int k = 0; k < 4; ++k) {
            base[tid * 4 + k] = run;
            run += h[k];
        }
#pragma unroll
        for (int k = 0; k < 4; ++k)
            if (h[k]) gbase[tid * 4 + k] = atomicAdd(&cursor[tid * 4 + k], h[k]);
    }
    __syncthreads();

    // ---- D: scatter into sorted LDS buffer (NO atomics: rank known) ----
#pragma unroll
    for (int q = 0; q < EPT; ++q) {
        if (bnrk[q] != 0xFFFFFFFFu) {
            const unsigned b   = bnrk[q] >> 16;
            const unsigned pos = base[b] + (bnrk[q] & 0xFFFFu);
            sorted[pos] = ent[q];
            sbin[pos]   = (unsigned char)b;
        }
    }
    __syncthreads();

    // ---- E: coalesced write-out (contiguous run per bin) ----
    for (int l = tid; l < nval; l += 256) {
        const unsigned b    = sbin[l];
        const unsigned gpos = gbase[b] + ((unsigned)l - base[b]);
        if (gpos < (b + 1u) * CAP)          // ~9-sigma overflow guard
            bins[gpos] = sorted[l];
    }
}

__global__ __launch_bounds__(1024) void reduce_bins(
        const float* __restrict__ theta, const unsigned* __restrict__ bins,
        const unsigned* __restrict__ cursor, const float* __restrict__ v0p,
        const float* __restrict__ w0p, float* __restrict__ out, int N)
{
    __shared__ float th[BIN_W];                         //  8 KB
    __shared__ unsigned long long acc[BIN_W];           // 16 KB
    const int b     = blockIdx.x;
    const int tid   = threadIdx.x;
    const int node0 = b * BIN_W;
    const int W     = min(BIN_W, N - node0);

    for (int j = tid; j < BIN_W; j += 1024) {
        th[j]  = (j < W) ? theta[node0 + j] : 0.f;
        acc[j] = 0ull;
    }
    __syncthreads();

    const unsigned  base  = (unsigned)b * CAP;
    const int       count = (int)(cursor[b] - base);
    const unsigned* bp    = bins + base;

    // stream 8 entries/thread/iter via two unit-stride nontemporal uint4 loads
    const int CH = 1024 * 8;
    int i0 = 0;
    for (; i0 + CH <= count; i0 += CH) {
        const uint4_v ea = __builtin_nontemporal_load(
            (const uint4_v*)(bp + i0 + tid * 4));
        const uint4_v eb = __builtin_nontemporal_load(
            (const uint4_v*)(bp + i0 + 4096 + tid * 4));
        const unsigned ee[8] = {ea.x, ea.y, ea.z, ea.w, eb.x, eb.y, eb.z, eb.w};
#pragma unroll
        for (int k = 0; k < 8; ++k) {
            const unsigned e = ee[k];
            const unsigned l = e >> NBITS_Q;
            const float ts = (float)(e & Q_MASK) * Q_INV - 8.0f;
            const float r  = (ts - th[l]) * INV_2PI;
            const float sn = __builtin_amdgcn_sinf(r);
            const float cs = __builtin_amdgcn_cosf(r);
            const unsigned cq = (unsigned)((cs + 1.0f) * SCALE_F + 0.5f);
            const unsigned sq = (unsigned)((sn + 1.0f) * SCALE_F + 0.5f);
            atomicAdd(&acc[l], (1ull << 56) | ((unsigned long long)cq << 28)
                               | (unsigned long long)sq);
        }
    }
    for (int i = i0 + tid; i < count; i += 1024) {
        const unsigned e = __builtin_nontemporal_load(bp + i);
        const unsigned l = e >> NBITS_Q;
        const float ts = (float)(e & Q_MASK) * Q_INV - 8.0f;
        const float r  = (ts - th[l]) * INV_2PI;
        const float sn = __builtin_amdgcn_sinf(r);
        const float cs = __builtin_amdgcn_cosf(r);
        const unsigned cq = (unsigned)((cs + 1.0f) * SCALE_F + 0.5f);
        const unsigned sq = (unsigned)((sn + 1.0f) * SCALE_F + 0.5f);
        atomicAdd(&acc[l], (1ull << 56) | ((unsigned long long)cq << 28)
                           | (unsigned long long)sq);
    }
    __syncthreads();

    // epilogue: unpack, v and torque (th[] is exact fp32 theta)
    const float v0 = *v0p, w0 = *w0p;
    for (int j = tid; j < W; j += 1024) {
        const float t  = th[j];
        const float rr = t * INV_2PI;
        const float sn = __builtin_amdgcn_sinf(rr);
        const float cs = __builtin_amdgcn_cosf(rr);
        ((float2*)out)[node0 + j] = make_float2(v0 * cs, v0 * sn);
        const unsigned long long P = acc[j];
        const float c  = (float)(unsigned)(P >> 56);
        const float xs = (float)(unsigned)((P >> 28) & 0xFFFFFFFull) * INV_SCALE - c;
        const float ys = (float)(unsigned)(P & 0xFFFFFFFull) * INV_SCALE - c;
        const float nrm = sqrtf(xs * xs + ys * ys);
        out[2 * N + node0 + j] = w0 * (ys / fmaxf(nrm, 1e-12f));
    }
}

// ---------- fallback path (round-2 kernels) if ws is too small ----------

__global__ void zero_ws_kernel(float4* __restrict__ ws, int n4) {
    int i = blockIdx.x * blockDim.x + threadIdx.x;
    if (i < n4) ws[i] = make_float4(0.f, 0.f, 0.f, 0.f);
}

__global__ void edge_kernel_fb(const float* __restrict__ theta,
                               const int4* __restrict__ src4,
                               const int4* __restrict__ dst4,
                               float2* __restrict__ acc, int E8) {
    int i = blockIdx.x * blockDim.x + threadIdx.x;
    if (i >= E8) return;
    const int4 s0 = src4[2 * i], s1 = src4[2 * i + 1];
    const int4 d0 = dst4[2 * i], d1 = dst4[2 * i + 1];
    const int ss[8] = {s0.x, s0.y, s0.z, s0.w, s1.x, s1.y, s1.z, s1.w};
    const int dd[8] = {d0.x, d0.y, d0.z, d0.w, d1.x, d1.y, d1.z, d1.w};
    float ts[8], td[8];
#pragma unroll
    for (int k = 0; k < 8; ++k) ts[k] = theta[ss[k]];
#pragma unroll
    for (int k = 0; k < 8; ++k) td[k] = theta[dd[k]];
#pragma unroll
    for (int k = 0; k < 8; ++k) {
        float sn, cs;
        __sincosf(ts[k] - td[k], &sn, &cs);
        atomicAdd(&acc[dd[k]].x, cs);
        atomicAdd(&acc[dd[k]].y, sn);
    }
}

__global__ void node_kernel_fb(const float* __restrict__ theta,
                               const float2* __restrict__ acc,
                               const float* __restrict__ v0p,
                               const float* __restrict__ w0p,
                               float* __restrict__ out, int N) {
    int i = blockIdx.x * blockDim.x + threadIdx.x;
    if (i >= N) return;
    const float v0 = *v0p, w0 = *w0p;
    float sn, cs;
    __sincosf(theta[i], &sn, &cs);
    ((float2*)out)[i] = make_float2(v0 * cs, v0 * sn);
    const float2 a = acc[i];
    const float nrm = sqrtf(a.x * a.x + a.y * a.y);
    out[2 * N + i] = w0 * (a.y / fmaxf(nrm, 1e-12f));
}

extern "C" void kernel_launch(void* const* d_in, const int* in_sizes, int n_in,
                              void* d_out, int out_size, void* d_ws, size_t ws_size,
                              hipStream_t stream) {
    const float* theta = (const float*)d_in[0];
    const int*   src   = (const int*)d_in[1];
    const int*   dst   = (const int*)d_in[2];
    const float* v0p   = (const float*)d_in[3];
    const float* w0p   = (const float*)d_in[4];
    float*       out   = (float*)d_out;

    const int N = in_sizes[0];   // 500,000
    const int E = in_sizes[1];   // 16,000,000

    const size_t need = 1024 + (size_t)NB * CAP * sizeof(unsigned);

    if (ws_size >= need && N <= NB * BIN_W) {
        unsigned* cursor = (unsigned*)d_ws;
        unsigned* bins   = cursor + 256;

        init_cursors<<<1, 256, 0, stream>>>(cursor);

        const int nblk = (E + K_BATCH - 1) / K_BATCH;   // 1954
        bin_edges_sort<<<nblk, 256, 0, stream>>>(theta, (const int4*)src,
                                                 (const int4*)dst,
                                                 bins, cursor, E);

        const int nbins = (N + BIN_W - 1) / BIN_W;      // 245
        reduce_bins<<<nbins, 1024, 0, stream>>>(theta, bins, cursor,
                                                v0p, w0p, out, N);
    } else {
        float2* acc = (float2*)d_ws;
        {
            const int n4 = (2 * N) / 4;
            zero_ws_kernel<<<(n4 + 255) / 256, 256, 0, stream>>>((float4*)d_ws, n4);
        }
        {
            const int E8 = E / 8;
            edge_kernel_fb<<<(E8 + 255) / 256, 256, 0, stream>>>(
                theta, (const int4*)src, (const int4*)dst, acc, E8);
        }
        node_kernel_fb<<<(N + 255) / 256, 256, 0, stream>>>(theta, acc, v0p, w0p,
                                                            out, N);
    }
}